// Round 14
// baseline (484.377 us; speedup 1.0000x reference)
//
#include <hip/hip_runtime.h>
#include <hip/hip_bf16.h>
#include <stdint.h>

#define N_NODES 50000
#define N_EDGES 800000
#define FEAT 128
#define CAP 64          // bucket capacity per node (in-degree Poisson(16); P(>=64)~1e-20)
#define NCVT 1600000    // N*FEAT/4 half4 units (block-aligned: /256 = 6250)
#define NTRW 163840     // 10*16384 (W0, W1 only; W2 enters via v_k)
#define NPRE (NCVT + NTRW)
#define NXCD 8
#define RNG 6250        // ceil(N_NODES/NXCD)

typedef __attribute__((ext_vector_type(4))) float floatx4;
typedef __attribute__((ext_vector_type(8))) _Float16 half8;
typedef __attribute__((ext_vector_type(4))) _Float16 half4;

__device__ __forceinline__ float bf2f(unsigned short u) {
  union { unsigned u; float f; } v; v.u = ((unsigned)u) << 16; return v.f;
}
__device__ __forceinline__ unsigned short f2bf(float f) {
  union { float f; unsigned u; } v; v.f = f;
  unsigned r = v.u + 0x7fffu + ((v.u >> 16) & 1u);
  return (unsigned short)(r >> 16);
}
__device__ __forceinline__ unsigned pack_edge(float w, int s) {
  _Float16 h = (_Float16)w;
  unsigned short hb = __builtin_bit_cast(unsigned short, h);
  return ((unsigned)s << 16) | (unsigned)hb;
}
__device__ __forceinline__ float edge_w(unsigned e) {
  unsigned short hb = (unsigned short)(e & 0xFFFFu);
  return (float)__builtin_bit_cast(_Float16, hb);
}
__device__ __forceinline__ int edge_src(unsigned e) { return (int)(e >> 16); }

// ---- pre1 (single block, cheap): dtype detect + params->fp32 ----
// pf: [0..127]=b0 [128..255]=b1 [256..383]=b2 [384..511]=wl [512]=bl
//     [520..1159]=v (5x128, v_k = W2_k @ Wl)  [1160]=const (b2.Wl + bl)
__global__ void k_pre1(const unsigned short* __restrict__ x,
                       const void* b0, const void* b1, const void* b2,
                       const void* wl, const void* bl,
                       float* __restrict__ pf, int* __restrict__ flag) {
  __shared__ int cnt_s;
  __shared__ int fl_s;
  int tid = threadIdx.x;
  if (tid == 0) cnt_s = 0;
  __syncthreads();
  int big = 0;
  for (int i = tid; i < 4096; i += 256) {
    unsigned short u = x[2 * i];
    int e = (u >> 7) & 0xFF;
    if (e >= 0xE0) big++;
  }
  atomicAdd(&cnt_s, big);
  __syncthreads();
  if (tid == 0) { fl_s = (cnt_s > 16) ? 1 : 0; flag[0] = fl_s; }
  __syncthreads();
  int fl = fl_s;
  for (int i = tid; i < 513; i += 256) {
    const void* src; int off;
    if (i < 128)      { src = b0; off = i; }
    else if (i < 256) { src = b1; off = i - 128; }
    else if (i < 384) { src = b2; off = i - 256; }
    else if (i < 512) { src = wl; off = i - 384; }
    else              { src = bl; off = 0; }
    pf[i] = fl ? ((const float*)src)[off] : bf2f(((const unsigned short*)src)[off]);
  }
}

// ---- prev (3 blocks x 256): v_k = W2_k @ Wl + const ----
__global__ void k_prev(const void* __restrict__ w2, float* __restrict__ pf,
                       const int* __restrict__ flag) {
  int d = blockIdx.x * 256 + threadIdx.x;
  if (d > 640) return;
  int fl = flag[0];
  if (d < 640) {
    int k = d >> 7, f = d & 127;
    float s = 0.f;
    const int base = (k << 14) + (f << 7);
    if (fl) {
      const float* w = (const float*)w2 + base;
#pragma unroll 8
      for (int i = 0; i < 128; ++i) s += w[i] * pf[384 + i];
    } else {
      const unsigned short* w = (const unsigned short*)w2 + base;
#pragma unroll 8
      for (int i = 0; i < 128; ++i) s += bf2f(w[i]) * pf[384 + i];
    }
    pf[520 + d] = s;
  } else {
    float s = 0.f;
    for (int i = 0; i < 128; ++i) s += pf[256 + i] * pf[384 + i];
    pf[1160] = s + pf[512];
  }
}

// ---- pre2 (fused): x -> fp16 T0 + int8 shadow Q0/S0 | transpose W0,W1 ----
// In the NCVT region, a row (128 feats) = 32 consecutive lanes; quantization max
// via 5-step 32-lane shuffle reduce (NCVT is wave- and block-aligned).
__global__ void k_pre2(const void* __restrict__ xp,
                       const void* __restrict__ w0, const void* __restrict__ w1,
                       _Float16* __restrict__ t0,
                       unsigned char* __restrict__ q0, float* __restrict__ s0,
                       _Float16* __restrict__ wt,
                       const int* __restrict__ flag) {
  int i = blockIdx.x * blockDim.x + threadIdx.x;
  int fl = flag[0];
  if (i < NCVT) {
    float4 o;
    if (fl) {
      o = ((const float4*)xp)[i];
    } else {
      ushort4 v = ((const ushort4*)xp)[i];
      o.x = bf2f(v.x); o.y = bf2f(v.y); o.z = bf2f(v.z); o.w = bf2f(v.w);
    }
    half4 h;
    h[0] = (_Float16)o.x; h[1] = (_Float16)o.y; h[2] = (_Float16)o.z; h[3] = (_Float16)o.w;
    ((half4*)t0)[i] = h;
    // int8 shadow (biased uint8, per-row scale)
    float mx = fmaxf(fmaxf(fabsf(o.x), fabsf(o.y)), fmaxf(fabsf(o.z), fabsf(o.w)));
#pragma unroll
    for (int d = 1; d < 32; d <<= 1) mx = fmaxf(mx, __shfl_xor(mx, d));
    float inv = mx > 0.f ? 127.f / mx : 0.f;
    int qa = (int)rintf(o.x * inv) + 128;
    int qb = (int)rintf(o.y * inv) + 128;
    int qc = (int)rintf(o.z * inv) + 128;
    int qd = (int)rintf(o.w * inv) + 128;
    ((unsigned*)q0)[i] = (unsigned)qa | ((unsigned)qb << 8) | ((unsigned)qc << 16) | ((unsigned)qd << 24);
    if ((i & 31) == 0) s0[i >> 5] = mx > 0.f ? mx / 127.f : 0.f;
  } else {
    int tid = i - NCVT;
    if (tid >= NTRW) return;
    int li = tid >> 14;           // 0..9
    int r = tid & 16383;
    int n = r >> 7, kk = r & 127;
    int l = li / 5, k = li - l * 5;
    const void* w = (l == 0) ? w0 : w1;
    int idx = k * 16384 + kk * 128 + n;
    float v = fl ? ((const float*)w)[idx] : bf2f(((const unsigned short*)w)[idx]);
    wt[tid] = (_Float16)v;
  }
}

// ---- deg, XCD-partitioned: group g = blockIdx&7 (lands on XCD g) owns src range g ----
// Each group scans all edges; deg counters touched by exactly one XCD -> L2-local atomics.
__global__ __launch_bounds__(256) void k_deg8(const int* __restrict__ src,
                                              const int* __restrict__ dst,
                                              int* __restrict__ deg) {
  int g = blockIdx.x & 7;
  int lo = g * RNG, hi = lo + RNG; if (hi > N_NODES) hi = N_NODES;
  int nb = gridDim.x >> 3;
  int bi = blockIdx.x >> 3;
  for (int e = bi * 256 + threadIdx.x; e < N_EDGES; e += nb * 256) {
    int s = src[e];
    if (s >= lo && s < hi && s != dst[e]) atomicAdd(&deg[s], 1);
  }
}

// ---- fill, XCD-partitioned by dst range: bucket lines stay in one XCD's L2 ----
__global__ __launch_bounds__(256) void k_fill8(const int* __restrict__ src,
                                               const int* __restrict__ dst,
                                               const int* __restrict__ deg,
                                               int* __restrict__ cnt,
                                               unsigned* __restrict__ edata) {
  int g = blockIdx.x & 7;
  int lo = g * RNG, hi = lo + RNG; if (hi > N_NODES) hi = N_NODES;
  int nb = gridDim.x >> 3;
  int bi = blockIdx.x >> 3;
  for (int e = bi * 256 + threadIdx.x; e < N_EDGES; e += nb * 256) {
    int d = dst[e];
    if (d < lo || d >= hi) continue;
    int s = src[e];
    if (s == d) continue;
    int ds = deg[s], dd = deg[d];
    float w = (ds > 0 && dd > 0) ? -rsqrtf((float)ds) * rsqrtf((float)dd) : 0.f;
    int pos = atomicAdd(&cnt[d], 1);
    if (pos < CAP) edata[(d << 6) + pos] = pack_edge(w, s);
  }
}

// ---- feature SpMV: gathers biased-uint8 rows (128B) + scale[src] (L2-resident).
// Sum w*x_hat = sum(w*s)*q - 128*sum(w*s). fp16 master Z/Y; optional int8 shadow out.
__global__ __launch_bounds__(256) void k_spmv(const unsigned* __restrict__ edata,
                                              const int* __restrict__ cnt,
                                              const unsigned char* __restrict__ Q,
                                              const float* __restrict__ S,
                                              const _Float16* __restrict__ Z,
                                              _Float16* __restrict__ Y,
                                              unsigned char* __restrict__ Qo,
                                              float* __restrict__ So,
                                              float alpha, int hasZ, int wshadow) {
  int wave = threadIdx.x >> 6, lane = threadIdx.x & 63;
  int q = lane >> 4, l16 = lane & 15;
  int node = blockIdx.x * 16 + wave * 4 + q;
  if (node >= N_NODES) return;
  int n_e = cnt[node]; if (n_e > CAP) n_e = CAP;
  int base = node << 6;

  float acc[8];
#pragma unroll
  for (int f = 0; f < 8; ++f) acc[f] = 0.f;
  float wsum = 0.f;

  unsigned e0 = (0 < n_e) ? edata[base + 0] : 0u;
  unsigned e1 = (1 < n_e) ? edata[base + 1] : 0u;
  unsigned e2 = (2 < n_e) ? edata[base + 2] : 0u;
  unsigned e3 = (3 < n_e) ? edata[base + 3] : 0u;
  unsigned e4 = (4 < n_e) ? edata[base + 4] : 0u;
  unsigned e5 = (5 < n_e) ? edata[base + 5] : 0u;
  unsigned e6 = (6 < n_e) ? edata[base + 6] : 0u;
  unsigned e7 = (7 < n_e) ? edata[base + 7] : 0u;
  uint2 r0 = ((const uint2*)(Q + (size_t)edge_src(e0) * FEAT))[l16];
  uint2 r1 = ((const uint2*)(Q + (size_t)edge_src(e1) * FEAT))[l16];
  uint2 r2 = ((const uint2*)(Q + (size_t)edge_src(e2) * FEAT))[l16];
  uint2 r3 = ((const uint2*)(Q + (size_t)edge_src(e3) * FEAT))[l16];
  float s0 = S[edge_src(e0)], s1 = S[edge_src(e1)], s2 = S[edge_src(e2)], s3 = S[edge_src(e3)];

  for (int j = 0; j < n_e; j += 4) {
    float ws0 = edge_w(e0) * s0, ws1 = edge_w(e1) * s1;
    float ws2 = edge_w(e2) * s2, ws3 = edge_w(e3) * s3;
    uint2 c0 = r0, c1 = r1, c2 = r2, c3 = r3;
    e0 = e4; e1 = e5; e2 = e6; e3 = e7;
    e4 = (j + 8 < n_e) ? edata[base + j + 8] : 0u;
    e5 = (j + 9 < n_e) ? edata[base + j + 9] : 0u;
    e6 = (j + 10 < n_e) ? edata[base + j + 10] : 0u;
    e7 = (j + 11 < n_e) ? edata[base + j + 11] : 0u;
    r0 = ((const uint2*)(Q + (size_t)edge_src(e0) * FEAT))[l16];
    r1 = ((const uint2*)(Q + (size_t)edge_src(e1) * FEAT))[l16];
    r2 = ((const uint2*)(Q + (size_t)edge_src(e2) * FEAT))[l16];
    r3 = ((const uint2*)(Q + (size_t)edge_src(e3) * FEAT))[l16];
    s0 = S[edge_src(e0)]; s1 = S[edge_src(e1)]; s2 = S[edge_src(e2)]; s3 = S[edge_src(e3)];
#define DEC8(c, w)                                                        \
    acc[0] = fmaf(w, (float)(c.x & 0xFFu), acc[0]);                       \
    acc[1] = fmaf(w, (float)((c.x >> 8) & 0xFFu), acc[1]);                \
    acc[2] = fmaf(w, (float)((c.x >> 16) & 0xFFu), acc[2]);               \
    acc[3] = fmaf(w, (float)(c.x >> 24), acc[3]);                         \
    acc[4] = fmaf(w, (float)(c.y & 0xFFu), acc[4]);                       \
    acc[5] = fmaf(w, (float)((c.y >> 8) & 0xFFu), acc[5]);                \
    acc[6] = fmaf(w, (float)((c.y >> 16) & 0xFFu), acc[6]);               \
    acc[7] = fmaf(w, (float)(c.y >> 24), acc[7]);
    DEC8(c0, ws0) DEC8(c1, ws1) DEC8(c2, ws2) DEC8(c3, ws3)
#undef DEC8
    wsum += (ws0 + ws1) + (ws2 + ws3);
  }
  float rx[8];
  float b128 = 128.f * wsum;
  if (hasZ) {
    half8 z = ((const half8*)(Z + (size_t)node * FEAT))[l16];
#pragma unroll
    for (int f = 0; f < 8; ++f) rx[f] = fmaf(alpha, acc[f] - b128, -(float)z[f]);
  } else {
#pragma unroll
    for (int f = 0; f < 8; ++f) rx[f] = alpha * (acc[f] - b128);
  }
  half8 res;
#pragma unroll
  for (int f = 0; f < 8; ++f) res[f] = (_Float16)rx[f];
  ((half8*)(Y + (size_t)node * FEAT))[l16] = res;
  if (wshadow) {
    float mx = 0.f;
#pragma unroll
    for (int f = 0; f < 8; ++f) mx = fmaxf(mx, fabsf(rx[f]));
#pragma unroll
    for (int o = 1; o < 16; o <<= 1) mx = fmaxf(mx, __shfl_xor(mx, o));
    float inv = mx > 0.f ? 127.f / mx : 0.f;
    int qb[8];
#pragma unroll
    for (int f = 0; f < 8; ++f) qb[f] = (int)rintf(rx[f] * inv) + 128;
    uint2 p;
    p.x = (unsigned)qb[0] | ((unsigned)qb[1] << 8) | ((unsigned)qb[2] << 16) | ((unsigned)qb[3] << 24);
    p.y = (unsigned)qb[4] | ((unsigned)qb[5] << 8) | ((unsigned)qb[6] << 16) | ((unsigned)qb[7] << 24);
    ((uint2*)(Qo + (size_t)node * FEAT))[l16] = p;
    if (l16 == 0) So[node] = mx > 0.f ? mx / 127.f : 0.f;
  }
}

// ---- scalar SpMV (Clenshaw step): y[n] = h[n] + cL*sum w_e*b[src] - bprev[n] ----
__global__ __launch_bounds__(256) void k_smv(const unsigned* __restrict__ edata,
                                             const int* __restrict__ cnt,
                                             const float* __restrict__ h,
                                             const float* __restrict__ b,
                                             const float* __restrict__ bprev,
                                             float cL, float* __restrict__ y,
                                             int is_out, void* __restrict__ outp,
                                             const int* __restrict__ flag,
                                             const float* __restrict__ cptr) {
  int wave = threadIdx.x >> 6, lane = threadIdx.x & 63;
  int q = lane >> 4, l16 = lane & 15;
  int node = blockIdx.x * 16 + wave * 4 + q;
  if (node >= N_NODES) return;
  int n_e = cnt[node]; if (n_e > CAP) n_e = CAP;
  int base = node << 6;
  float s = 0.f;
  for (int j = l16; j < n_e; j += 16) {
    unsigned e = edata[base + j];
    s = fmaf(edge_w(e), b[edge_src(e)], s);
  }
#pragma unroll
  for (int o = 1; o < 16; o <<= 1) s += __shfl_xor(s, o);
  if (l16 == 0) {
    float r = fmaf(cL, s, h[node]) - (bprev ? bprev[node] : 0.f);
    if (!is_out) {
      y[node] = r;
    } else {
      r += cptr[0];
      if (flag[0]) ((float*)outp)[node] = r;
      else ((unsigned short*)outp)[node] = f2bf(r);
    }
  }
}

// ---- fused layer GEMM (f16 MFMA): relu(sum_k T_k @ W_k + bias) ----
// mode 0: write relu rows to dst (fp16) + int8 shadow (q8, sc).
// mode 1: NO row write; h[k][m] = relu_row . v_k for k=0..4 (layer-2 collapse).
__global__ __launch_bounds__(256) void k_gemm(const _Float16* __restrict__ t0, const _Float16* __restrict__ t1,
                                              const _Float16* __restrict__ t2, const _Float16* __restrict__ t3,
                                              const _Float16* __restrict__ t4,
                                              const _Float16* __restrict__ wt,  // [5][128(n)][128(k)] fp16
                                              const float* __restrict__ bias,
                                              _Float16* __restrict__ dst, int mode,
                                              const float* __restrict__ v0,   // 5x128
                                              float* __restrict__ hout,       // 5xN
                                              unsigned char* __restrict__ q8,
                                              float* __restrict__ sc) {
  __shared__ _Float16 lb[128 * 136];
  const _Float16* tp[5] = {t0, t1, t2, t3, t4};
  int tid = threadIdx.x, wave = tid >> 6, lane = tid & 63;
  int quad = lane >> 4, l16 = lane & 15;
  int m0 = blockIdx.x * 128;
  floatx4 acc[2][8];
#pragma unroll
  for (int s = 0; s < 2; ++s)
#pragma unroll
    for (int j = 0; j < 8; ++j) acc[s][j] = (floatx4){0.f, 0.f, 0.f, 0.f};
  int arow[2];
  bool aval[2];
#pragma unroll
  for (int s = 0; s < 2; ++s) {
    arow[s] = m0 + wave * 32 + s * 16 + l16;
    aval[s] = arow[s] < N_NODES;
  }

#pragma unroll
  for (int k = 0; k < 5; ++k) {
    __syncthreads();
    {
      int n = tid >> 1, half = tid & 1;
      const uint4* sp = (const uint4*)(wt + k * 16384 + n * 128 + half * 64);
      uint4* dq = (uint4*)(lb + n * 136 + half * 64);
#pragma unroll
      for (int i = 0; i < 8; ++i) dq[i] = sp[i];
    }
    __syncthreads();
    const _Float16* A = tp[k];
#pragma unroll
    for (int ki = 0; ki < 4; ++ki) {
      half8 af[2];
#pragma unroll
      for (int s = 0; s < 2; ++s) {
        if (aval[s]) {
          af[s] = *((const half8*)(A + (size_t)arow[s] * FEAT + ki * 32 + quad * 8));
        } else {
#pragma unroll
          for (int i = 0; i < 8; ++i) af[s][i] = (_Float16)0.f;
        }
      }
#pragma unroll
      for (int j = 0; j < 8; ++j) {
        half8 bf = *((const half8*)(lb + (j * 16 + l16) * 136 + ki * 32 + quad * 8));
        acc[0][j] = __builtin_amdgcn_mfma_f32_16x16x32_f16(af[0], bf, acc[0][j], 0, 0, 0);
        acc[1][j] = __builtin_amdgcn_mfma_f32_16x16x32_f16(af[1], bf, acc[1][j], 0, 0, 0);
      }
    }
  }
#pragma unroll
  for (int s = 0; s < 2; ++s) {
    int rbase = m0 + wave * 32 + s * 16 + quad * 4;
    if (mode == 0) {
      float mx[4] = {0.f, 0.f, 0.f, 0.f};
#pragma unroll
      for (int j = 0; j < 8; ++j) {
        int col = j * 16 + l16;
        float b = bias[col];
#pragma unroll
        for (int r = 0; r < 4; ++r) {
          int m = rbase + r;
          float v = fmaxf(acc[s][j][r] + b, 0.f);
          if (m < N_NODES) dst[(size_t)m * FEAT + col] = (_Float16)v;
          mx[r] = fmaxf(mx[r], v);
        }
      }
#pragma unroll
      for (int o = 1; o < 16; o <<= 1) {
#pragma unroll
        for (int r = 0; r < 4; ++r) mx[r] = fmaxf(mx[r], __shfl_xor(mx[r], o));
      }
      float inv[4];
#pragma unroll
      for (int r = 0; r < 4; ++r) inv[r] = mx[r] > 0.f ? 127.f / mx[r] : 0.f;
      if (l16 == 0) {
#pragma unroll
        for (int r = 0; r < 4; ++r) {
          int m = rbase + r;
          if (m < N_NODES) sc[m] = mx[r] > 0.f ? mx[r] / 127.f : 0.f;
        }
      }
#pragma unroll
      for (int j = 0; j < 8; ++j) {
        int col = j * 16 + l16;
        float b = bias[col];
#pragma unroll
        for (int r = 0; r < 4; ++r) {
          int m = rbase + r;
          if (m < N_NODES) {
            float v = fmaxf(acc[s][j][r] + b, 0.f);
            int qv = (int)rintf(v * inv[r]) + 128;
            q8[(size_t)m * FEAT + col] = (unsigned char)qv;
          }
        }
      }
    } else {
      float p[5][4];
#pragma unroll
      for (int k = 0; k < 5; ++k)
#pragma unroll
        for (int r = 0; r < 4; ++r) p[k][r] = 0.f;
#pragma unroll
      for (int j = 0; j < 8; ++j) {
        int col = j * 16 + l16;
        float b = bias[col];
        float vv[5];
#pragma unroll
        for (int k = 0; k < 5; ++k) vv[k] = v0[k * 128 + col];
#pragma unroll
        for (int r = 0; r < 4; ++r) {
          float val = fmaxf(acc[s][j][r] + b, 0.f);
#pragma unroll
          for (int k = 0; k < 5; ++k) p[k][r] = fmaf(val, vv[k], p[k][r]);
        }
      }
#pragma unroll
      for (int o = 1; o < 16; o <<= 1) {
#pragma unroll
        for (int k = 0; k < 5; ++k)
#pragma unroll
          for (int r = 0; r < 4; ++r) p[k][r] += __shfl_xor(p[k][r], o);
      }
      if (l16 == 0) {
#pragma unroll
        for (int r = 0; r < 4; ++r) {
          int m = rbase + r;
          if (m < N_NODES) {
#pragma unroll
            for (int k = 0; k < 5; ++k) hout[k * N_NODES + m] = p[k][r];
          }
        }
      }
    }
  }
}

extern "C" void kernel_launch(void* const* d_in, const int* in_sizes, int n_in,
                              void* d_out, int out_size, void* d_ws, size_t ws_size,
                              hipStream_t stream) {
  const void* x  = d_in[0];
  const int* ei  = (const int*)d_in[1];
  const void* w0 = d_in[2];
  const void* b0 = d_in[3];
  const void* w1 = d_in[4];
  const void* b1 = d_in[5];
  const void* w2 = d_in[6];
  const void* b2 = d_in[7];
  const void* wl = d_in[8];
  const void* bl = d_in[9];
  const int* src = ei;
  const int* dst = ei + N_EDGES;

  char* ws = (char*)d_ws;
  size_t off = 0;
  auto alloc = [&](size_t bytes) -> char* {
    char* p = ws + off;
    off += (bytes + 255) & ~(size_t)255;
    return p;
  };
  _Float16* T[5];
  for (int i = 0; i < 5; ++i) T[i] = (_Float16*)alloc(sizeof(_Float16) * N_NODES * FEAT);  // fp16 masters
  unsigned char* Q[5];
  for (int i = 0; i < 5; ++i) Q[i] = (unsigned char*)alloc((size_t)N_NODES * FEAT);        // int8 shadows
  float* S[5];
  for (int i = 0; i < 5; ++i) S[i] = (float*)alloc(sizeof(float) * N_NODES);               // row scales
  unsigned* edata = (unsigned*)alloc(sizeof(unsigned) * N_NODES * CAP);                    // 12.8 MB
  int* cnt = (int*)alloc(sizeof(int) * N_NODES * 2);  // cnt, deg contiguous (one memset)
  int* deg = cnt + N_NODES;
  _Float16* wt = (_Float16*)alloc(sizeof(_Float16) * NTRW);
  float* pf = (float*)alloc(sizeof(float) * 1536);
  float* hbuf = (float*)alloc(sizeof(float) * 5 * N_NODES);  // h_k = relu(H1).v_k
  float* bbuf = (float*)alloc(sizeof(float) * 3 * N_NODES);  // Clenshaw b3,b2,b1
  int* flag = (int*)alloc(sizeof(int));

  hipMemsetAsync(cnt, 0, sizeof(int) * N_NODES * 2, stream);
  k_pre1<<<1, 256, 0, stream>>>((const unsigned short*)x, b0, b1, b2, wl, bl, pf, flag);
  k_prev<<<3, 256, 0, stream>>>(w2, pf, flag);
  k_pre2<<<(NPRE + 255) / 256, 256, 0, stream>>>(x, w0, w1, T[0], Q[0], S[0], wt, flag);
  k_deg8<<<512, 256, 0, stream>>>(src, dst, deg);
  k_fill8<<<512, 256, 0, stream>>>(src, dst, deg, cnt, edata);

  int nblk_spmv = (N_NODES + 15) / 16;
  int nblk_gemm = (N_NODES + 127) / 128;
  const float* v = pf + 520;       // v_k, 5x128
  const float* cc = pf + 1160;     // b2.Wl + bl

  // layers 0,1: ChebConv via int8-shadow gathers; layer-0 GEMM -> relu rows (+shadow),
  // layer-1 GEMM -> h_k scalars only.
  for (int l = 0; l < 2; ++l) {
    k_spmv<<<nblk_spmv, 256, 0, stream>>>(edata, cnt, Q[0], S[0], nullptr, T[1], Q[1], S[1], 1.f, 0, 1);
    k_spmv<<<nblk_spmv, 256, 0, stream>>>(edata, cnt, Q[1], S[1], T[0], T[2], Q[2], S[2], 2.f, 1, 1);
    k_spmv<<<nblk_spmv, 256, 0, stream>>>(edata, cnt, Q[2], S[2], T[1], T[3], Q[3], S[3], 2.f, 1, 1);
    k_spmv<<<nblk_spmv, 256, 0, stream>>>(edata, cnt, Q[3], S[3], T[2], T[4], nullptr, nullptr, 2.f, 1, 0);
    k_gemm<<<nblk_gemm, 256, 0, stream>>>(T[0], T[1], T[2], T[3], T[4],
                                          wt + l * 5 * 16384, pf + l * 128, T[0],
                                          l, v, hbuf, Q[0], S[0]);
  }
  // layer 2 via Clenshaw on scalar fields (fp32)
  float* h0 = hbuf;
  float* h1 = hbuf + N_NODES;
  float* h2 = hbuf + 2 * N_NODES;
  float* h3 = hbuf + 3 * N_NODES;
  float* h4 = hbuf + 4 * N_NODES;
  float* b3 = bbuf;
  float* b2c = bbuf + N_NODES;
  float* b1c = bbuf + 2 * N_NODES;
  k_smv<<<nblk_spmv, 256, 0, stream>>>(edata, cnt, h3, h4, nullptr, 2.f, b3, 0, nullptr, flag, nullptr);
  k_smv<<<nblk_spmv, 256, 0, stream>>>(edata, cnt, h2, b3, h4, 2.f, b2c, 0, nullptr, flag, nullptr);
  k_smv<<<nblk_spmv, 256, 0, stream>>>(edata, cnt, h1, b2c, b3, 2.f, b1c, 0, nullptr, flag, nullptr);
  k_smv<<<nblk_spmv, 256, 0, stream>>>(edata, cnt, h0, b1c, b2c, 1.f, nullptr, 1, d_out, flag, cc);
}

// Round 15
// 448.666 us; speedup vs baseline: 1.0796x; 1.0796x over previous
//
#include <hip/hip_runtime.h>
#include <hip/hip_bf16.h>
#include <stdint.h>

#define N_NODES 50000
#define N_EDGES 800000
#define FEAT 128
#define CAP 64          // bucket capacity per node (in-degree Poisson(16); P(>=64)~1e-20)
#define NCVT 1600000    // N*FEAT/4 half4 units (block-aligned: /256 = 6250)
#define NTRW 163840     // 10*16384 (W0, W1 only; W2 enters via v_k) — block-aligned
#define NPRE (NCVT + NTRW + N_EDGES)

typedef __attribute__((ext_vector_type(4))) float floatx4;
typedef __attribute__((ext_vector_type(8))) _Float16 half8;
typedef __attribute__((ext_vector_type(4))) _Float16 half4;

__device__ __forceinline__ float bf2f(unsigned short u) {
  union { unsigned u; float f; } v; v.u = ((unsigned)u) << 16; return v.f;
}
__device__ __forceinline__ unsigned short f2bf(float f) {
  union { float f; unsigned u; } v; v.f = f;
  unsigned r = v.u + 0x7fffu + ((v.u >> 16) & 1u);
  return (unsigned short)(r >> 16);
}
__device__ __forceinline__ unsigned pack_edge(float w, int s) {
  _Float16 h = (_Float16)w;
  unsigned short hb = __builtin_bit_cast(unsigned short, h);
  return ((unsigned)s << 16) | (unsigned)hb;
}
__device__ __forceinline__ float edge_w(unsigned e) {
  unsigned short hb = (unsigned short)(e & 0xFFFFu);
  return (float)__builtin_bit_cast(_Float16, hb);
}
__device__ __forceinline__ int edge_src(unsigned e) { return (int)(e >> 16); }

// ---- pre1 (single block, cheap): dtype detect + params->fp32 ----
// pf: [0..127]=b0 [128..255]=b1 [256..383]=b2 [384..511]=wl [512]=bl
//     [520..1159]=v (5x128, v_k = W2_k @ Wl)  [1160]=const (b2.Wl + bl)
__global__ void k_pre1(const unsigned short* __restrict__ x,
                       const void* b0, const void* b1, const void* b2,
                       const void* wl, const void* bl,
                       float* __restrict__ pf, int* __restrict__ flag) {
  __shared__ int cnt_s;
  __shared__ int fl_s;
  int tid = threadIdx.x;
  if (tid == 0) cnt_s = 0;
  __syncthreads();
  int big = 0;
  for (int i = tid; i < 4096; i += 256) {
    unsigned short u = x[2 * i];
    int e = (u >> 7) & 0xFF;
    if (e >= 0xE0) big++;
  }
  atomicAdd(&cnt_s, big);
  __syncthreads();
  if (tid == 0) { fl_s = (cnt_s > 16) ? 1 : 0; flag[0] = fl_s; }
  __syncthreads();
  int fl = fl_s;
  for (int i = tid; i < 513; i += 256) {
    const void* src; int off;
    if (i < 128)      { src = b0; off = i; }
    else if (i < 256) { src = b1; off = i - 128; }
    else if (i < 384) { src = b2; off = i - 256; }
    else if (i < 512) { src = wl; off = i - 384; }
    else              { src = bl; off = 0; }
    pf[i] = fl ? ((const float*)src)[off] : bf2f(((const unsigned short*)src)[off]);
  }
}

// ---- prev (3 blocks x 256): v_k = W2_k @ Wl + const ----
__global__ void k_prev(const void* __restrict__ w2, float* __restrict__ pf,
                       const int* __restrict__ flag) {
  int d = blockIdx.x * 256 + threadIdx.x;
  if (d > 640) return;
  int fl = flag[0];
  if (d < 640) {
    int k = d >> 7, f = d & 127;
    float s = 0.f;
    const int base = (k << 14) + (f << 7);
    if (fl) {
      const float* w = (const float*)w2 + base;
#pragma unroll 8
      for (int i = 0; i < 128; ++i) s += w[i] * pf[384 + i];
    } else {
      const unsigned short* w = (const unsigned short*)w2 + base;
#pragma unroll 8
      for (int i = 0; i < 128; ++i) s += bf2f(w[i]) * pf[384 + i];
    }
    pf[520 + d] = s;
  } else {
    float s = 0.f;
    for (int i = 0; i < 128; ++i) s += pf[256 + i] * pf[384 + i];
    pf[1160] = s + pf[512];
  }
}

// ---- pre2 (fused): x -> fp16 T0 + int8 shadow Q0/S0 | transpose W0,W1 | deg atomics ----
// NCVT and NTRW are block-aligned so the 32-lane quant shuffle groups never straddle.
__global__ void k_pre2(const void* __restrict__ xp,
                       const void* __restrict__ w0, const void* __restrict__ w1,
                       const int* __restrict__ esrc, const int* __restrict__ edst,
                       _Float16* __restrict__ t0,
                       unsigned char* __restrict__ q0, float* __restrict__ s0,
                       _Float16* __restrict__ wt,
                       int* __restrict__ deg,
                       const int* __restrict__ flag) {
  int i = blockIdx.x * blockDim.x + threadIdx.x;
  int fl = flag[0];
  if (i < NCVT) {
    float4 o;
    if (fl) {
      o = ((const float4*)xp)[i];
    } else {
      ushort4 v = ((const ushort4*)xp)[i];
      o.x = bf2f(v.x); o.y = bf2f(v.y); o.z = bf2f(v.z); o.w = bf2f(v.w);
    }
    half4 h;
    h[0] = (_Float16)o.x; h[1] = (_Float16)o.y; h[2] = (_Float16)o.z; h[3] = (_Float16)o.w;
    ((half4*)t0)[i] = h;
    // int8 shadow (biased uint8, per-row scale); row = 32 consecutive lanes
    float mx = fmaxf(fmaxf(fabsf(o.x), fabsf(o.y)), fmaxf(fabsf(o.z), fabsf(o.w)));
#pragma unroll
    for (int d = 1; d < 32; d <<= 1) mx = fmaxf(mx, __shfl_xor(mx, d));
    float inv = mx > 0.f ? 127.f / mx : 0.f;
    int qa = (int)rintf(o.x * inv) + 128;
    int qb = (int)rintf(o.y * inv) + 128;
    int qc = (int)rintf(o.z * inv) + 128;
    int qd = (int)rintf(o.w * inv) + 128;
    ((unsigned*)q0)[i] = (unsigned)qa | ((unsigned)qb << 8) | ((unsigned)qc << 16) | ((unsigned)qd << 24);
    if ((i & 31) == 0) s0[i >> 5] = mx > 0.f ? mx / 127.f : 0.f;
  } else if (i < NCVT + NTRW) {
    int tid = i - NCVT;
    int li = tid >> 14;           // 0..9
    int r = tid & 16383;
    int n = r >> 7, kk = r & 127;
    int l = li / 5, k = li - l * 5;
    const void* w = (l == 0) ? w0 : w1;
    int idx = k * 16384 + kk * 128 + n;
    float v = fl ? ((const float*)w)[idx] : bf2f(((const unsigned short*)w)[idx]);
    wt[tid] = (_Float16)v;
  } else {
    int e = i - (NCVT + NTRW);
    if (e >= N_EDGES) return;
    int s = esrc[e], d = edst[e];
    if (s != d) atomicAdd(&deg[s], 1);
  }
}

// ---- bucket fill (one pass, plain atomics): slot = cnt[d]++; edata = pack(w, src) ----
__global__ void k_fill(const int* __restrict__ src, const int* __restrict__ dst,
                       const int* __restrict__ deg,
                       int* __restrict__ cnt, unsigned* __restrict__ edata) {
  int e = blockIdx.x * blockDim.x + threadIdx.x;
  if (e >= N_EDGES) return;
  int s = src[e], d = dst[e];
  if (s == d) return;
  int ds = deg[s], dd = deg[d];
  float w = (ds > 0 && dd > 0) ? -rsqrtf((float)ds) * rsqrtf((float)dd) : 0.f;
  int pos = atomicAdd(&cnt[d], 1);
  if (pos < CAP) edata[(d << 6) + pos] = pack_edge(w, s);
}

// ---- feature SpMV: gathers biased-uint8 rows (128B) + scale[src] (L2-resident).
// Sum w*x_hat = sum(w*s)*q - 128*sum(w*s). fp16 master Z/Y; optional int8 shadow out.
__global__ __launch_bounds__(256) void k_spmv(const unsigned* __restrict__ edata,
                                              const int* __restrict__ cnt,
                                              const unsigned char* __restrict__ Q,
                                              const float* __restrict__ S,
                                              const _Float16* __restrict__ Z,
                                              _Float16* __restrict__ Y,
                                              unsigned char* __restrict__ Qo,
                                              float* __restrict__ So,
                                              float alpha, int hasZ, int wshadow) {
  int wave = threadIdx.x >> 6, lane = threadIdx.x & 63;
  int q = lane >> 4, l16 = lane & 15;
  int node = blockIdx.x * 16 + wave * 4 + q;
  if (node >= N_NODES) return;
  int n_e = cnt[node]; if (n_e > CAP) n_e = CAP;
  int base = node << 6;

  float acc[8];
#pragma unroll
  for (int f = 0; f < 8; ++f) acc[f] = 0.f;
  float wsum = 0.f;

  unsigned e0 = (0 < n_e) ? edata[base + 0] : 0u;
  unsigned e1 = (1 < n_e) ? edata[base + 1] : 0u;
  unsigned e2 = (2 < n_e) ? edata[base + 2] : 0u;
  unsigned e3 = (3 < n_e) ? edata[base + 3] : 0u;
  unsigned e4 = (4 < n_e) ? edata[base + 4] : 0u;
  unsigned e5 = (5 < n_e) ? edata[base + 5] : 0u;
  unsigned e6 = (6 < n_e) ? edata[base + 6] : 0u;
  unsigned e7 = (7 < n_e) ? edata[base + 7] : 0u;
  uint2 r0 = ((const uint2*)(Q + (size_t)edge_src(e0) * FEAT))[l16];
  uint2 r1 = ((const uint2*)(Q + (size_t)edge_src(e1) * FEAT))[l16];
  uint2 r2 = ((const uint2*)(Q + (size_t)edge_src(e2) * FEAT))[l16];
  uint2 r3 = ((const uint2*)(Q + (size_t)edge_src(e3) * FEAT))[l16];
  float s0 = S[edge_src(e0)], s1 = S[edge_src(e1)], s2 = S[edge_src(e2)], s3 = S[edge_src(e3)];

  for (int j = 0; j < n_e; j += 4) {
    float ws0 = edge_w(e0) * s0, ws1 = edge_w(e1) * s1;
    float ws2 = edge_w(e2) * s2, ws3 = edge_w(e3) * s3;
    uint2 c0 = r0, c1 = r1, c2 = r2, c3 = r3;
    e0 = e4; e1 = e5; e2 = e6; e3 = e7;
    e4 = (j + 8 < n_e) ? edata[base + j + 8] : 0u;
    e5 = (j + 9 < n_e) ? edata[base + j + 9] : 0u;
    e6 = (j + 10 < n_e) ? edata[base + j + 10] : 0u;
    e7 = (j + 11 < n_e) ? edata[base + j + 11] : 0u;
    r0 = ((const uint2*)(Q + (size_t)edge_src(e0) * FEAT))[l16];
    r1 = ((const uint2*)(Q + (size_t)edge_src(e1) * FEAT))[l16];
    r2 = ((const uint2*)(Q + (size_t)edge_src(e2) * FEAT))[l16];
    r3 = ((const uint2*)(Q + (size_t)edge_src(e3) * FEAT))[l16];
    s0 = S[edge_src(e0)]; s1 = S[edge_src(e1)]; s2 = S[edge_src(e2)]; s3 = S[edge_src(e3)];
#define DEC8(c, w)                                                        \
    acc[0] = fmaf(w, (float)(c.x & 0xFFu), acc[0]);                       \
    acc[1] = fmaf(w, (float)((c.x >> 8) & 0xFFu), acc[1]);                \
    acc[2] = fmaf(w, (float)((c.x >> 16) & 0xFFu), acc[2]);               \
    acc[3] = fmaf(w, (float)(c.x >> 24), acc[3]);                         \
    acc[4] = fmaf(w, (float)(c.y & 0xFFu), acc[4]);                       \
    acc[5] = fmaf(w, (float)((c.y >> 8) & 0xFFu), acc[5]);                \
    acc[6] = fmaf(w, (float)((c.y >> 16) & 0xFFu), acc[6]);               \
    acc[7] = fmaf(w, (float)(c.y >> 24), acc[7]);
    DEC8(c0, ws0) DEC8(c1, ws1) DEC8(c2, ws2) DEC8(c3, ws3)
#undef DEC8
    wsum += (ws0 + ws1) + (ws2 + ws3);
  }
  float rx[8];
  float b128 = 128.f * wsum;
  if (hasZ) {
    half8 z = ((const half8*)(Z + (size_t)node * FEAT))[l16];
#pragma unroll
    for (int f = 0; f < 8; ++f) rx[f] = fmaf(alpha, acc[f] - b128, -(float)z[f]);
  } else {
#pragma unroll
    for (int f = 0; f < 8; ++f) rx[f] = alpha * (acc[f] - b128);
  }
  half8 res;
#pragma unroll
  for (int f = 0; f < 8; ++f) res[f] = (_Float16)rx[f];
  ((half8*)(Y + (size_t)node * FEAT))[l16] = res;
  if (wshadow) {
    float mx = 0.f;
#pragma unroll
    for (int f = 0; f < 8; ++f) mx = fmaxf(mx, fabsf(rx[f]));
#pragma unroll
    for (int o = 1; o < 16; o <<= 1) mx = fmaxf(mx, __shfl_xor(mx, o));
    float inv = mx > 0.f ? 127.f / mx : 0.f;
    int qb[8];
#pragma unroll
    for (int f = 0; f < 8; ++f) qb[f] = (int)rintf(rx[f] * inv) + 128;
    uint2 p;
    p.x = (unsigned)qb[0] | ((unsigned)qb[1] << 8) | ((unsigned)qb[2] << 16) | ((unsigned)qb[3] << 24);
    p.y = (unsigned)qb[4] | ((unsigned)qb[5] << 8) | ((unsigned)qb[6] << 16) | ((unsigned)qb[7] << 24);
    ((uint2*)(Qo + (size_t)node * FEAT))[l16] = p;
    if (l16 == 0) So[node] = mx > 0.f ? mx / 127.f : 0.f;
  }
}

// ---- scalar SpMV (Clenshaw step): y[n] = h[n] + cL*sum w_e*b[src] - bprev[n] ----
__global__ __launch_bounds__(256) void k_smv(const unsigned* __restrict__ edata,
                                             const int* __restrict__ cnt,
                                             const float* __restrict__ h,
                                             const float* __restrict__ b,
                                             const float* __restrict__ bprev,
                                             float cL, float* __restrict__ y,
                                             int is_out, void* __restrict__ outp,
                                             const int* __restrict__ flag,
                                             const float* __restrict__ cptr) {
  int wave = threadIdx.x >> 6, lane = threadIdx.x & 63;
  int q = lane >> 4, l16 = lane & 15;
  int node = blockIdx.x * 16 + wave * 4 + q;
  if (node >= N_NODES) return;
  int n_e = cnt[node]; if (n_e > CAP) n_e = CAP;
  int base = node << 6;
  float s = 0.f;
  for (int j = l16; j < n_e; j += 16) {
    unsigned e = edata[base + j];
    s = fmaf(edge_w(e), b[edge_src(e)], s);
  }
#pragma unroll
  for (int o = 1; o < 16; o <<= 1) s += __shfl_xor(s, o);
  if (l16 == 0) {
    float r = fmaf(cL, s, h[node]) - (bprev ? bprev[node] : 0.f);
    if (!is_out) {
      y[node] = r;
    } else {
      r += cptr[0];
      if (flag[0]) ((float*)outp)[node] = r;
      else ((unsigned short*)outp)[node] = f2bf(r);
    }
  }
}

// ---- fused layer GEMM (f16 MFMA): relu(sum_k T_k @ W_k + bias) ----
// mode 0: write relu rows to dst (fp16) + int8 shadow (q8, sc).
// mode 1: NO row write; h[k][m] = relu_row . v_k for k=0..4 (layer-2 collapse).
__global__ __launch_bounds__(256) void k_gemm(const _Float16* __restrict__ t0, const _Float16* __restrict__ t1,
                                              const _Float16* __restrict__ t2, const _Float16* __restrict__ t3,
                                              const _Float16* __restrict__ t4,
                                              const _Float16* __restrict__ wt,  // [5][128(n)][128(k)] fp16
                                              const float* __restrict__ bias,
                                              _Float16* __restrict__ dst, int mode,
                                              const float* __restrict__ v0,   // 5x128
                                              float* __restrict__ hout,       // 5xN
                                              unsigned char* __restrict__ q8,
                                              float* __restrict__ sc) {
  __shared__ _Float16 lb[128 * 136];
  const _Float16* tp[5] = {t0, t1, t2, t3, t4};
  int tid = threadIdx.x, wave = tid >> 6, lane = tid & 63;
  int quad = lane >> 4, l16 = lane & 15;
  int m0 = blockIdx.x * 128;
  floatx4 acc[2][8];
#pragma unroll
  for (int s = 0; s < 2; ++s)
#pragma unroll
    for (int j = 0; j < 8; ++j) acc[s][j] = (floatx4){0.f, 0.f, 0.f, 0.f};
  int arow[2];
  bool aval[2];
#pragma unroll
  for (int s = 0; s < 2; ++s) {
    arow[s] = m0 + wave * 32 + s * 16 + l16;
    aval[s] = arow[s] < N_NODES;
  }

#pragma unroll
  for (int k = 0; k < 5; ++k) {
    __syncthreads();
    {
      int n = tid >> 1, half = tid & 1;
      const uint4* sp = (const uint4*)(wt + k * 16384 + n * 128 + half * 64);
      uint4* dq = (uint4*)(lb + n * 136 + half * 64);
#pragma unroll
      for (int i = 0; i < 8; ++i) dq[i] = sp[i];
    }
    __syncthreads();
    const _Float16* A = tp[k];
#pragma unroll
    for (int ki = 0; ki < 4; ++ki) {
      half8 af[2];
#pragma unroll
      for (int s = 0; s < 2; ++s) {
        if (aval[s]) {
          af[s] = *((const half8*)(A + (size_t)arow[s] * FEAT + ki * 32 + quad * 8));
        } else {
#pragma unroll
          for (int i = 0; i < 8; ++i) af[s][i] = (_Float16)0.f;
        }
      }
#pragma unroll
      for (int j = 0; j < 8; ++j) {
        half8 bf = *((const half8*)(lb + (j * 16 + l16) * 136 + ki * 32 + quad * 8));
        acc[0][j] = __builtin_amdgcn_mfma_f32_16x16x32_f16(af[0], bf, acc[0][j], 0, 0, 0);
        acc[1][j] = __builtin_amdgcn_mfma_f32_16x16x32_f16(af[1], bf, acc[1][j], 0, 0, 0);
      }
    }
  }
#pragma unroll
  for (int s = 0; s < 2; ++s) {
    int rbase = m0 + wave * 32 + s * 16 + quad * 4;
    if (mode == 0) {
      float mx[4] = {0.f, 0.f, 0.f, 0.f};
#pragma unroll
      for (int j = 0; j < 8; ++j) {
        int col = j * 16 + l16;
        float b = bias[col];
#pragma unroll
        for (int r = 0; r < 4; ++r) {
          int m = rbase + r;
          float v = fmaxf(acc[s][j][r] + b, 0.f);
          if (m < N_NODES) dst[(size_t)m * FEAT + col] = (_Float16)v;
          mx[r] = fmaxf(mx[r], v);
        }
      }
#pragma unroll
      for (int o = 1; o < 16; o <<= 1) {
#pragma unroll
        for (int r = 0; r < 4; ++r) mx[r] = fmaxf(mx[r], __shfl_xor(mx[r], o));
      }
      float inv[4];
#pragma unroll
      for (int r = 0; r < 4; ++r) inv[r] = mx[r] > 0.f ? 127.f / mx[r] : 0.f;
      if (l16 == 0) {
#pragma unroll
        for (int r = 0; r < 4; ++r) {
          int m = rbase + r;
          if (m < N_NODES) sc[m] = mx[r] > 0.f ? mx[r] / 127.f : 0.f;
        }
      }
#pragma unroll
      for (int j = 0; j < 8; ++j) {
        int col = j * 16 + l16;
        float b = bias[col];
#pragma unroll
        for (int r = 0; r < 4; ++r) {
          int m = rbase + r;
          if (m < N_NODES) {
            float v = fmaxf(acc[s][j][r] + b, 0.f);
            int qv = (int)rintf(v * inv[r]) + 128;
            q8[(size_t)m * FEAT + col] = (unsigned char)qv;
          }
        }
      }
    } else {
      float p[5][4];
#pragma unroll
      for (int k = 0; k < 5; ++k)
#pragma unroll
        for (int r = 0; r < 4; ++r) p[k][r] = 0.f;
#pragma unroll
      for (int j = 0; j < 8; ++j) {
        int col = j * 16 + l16;
        float b = bias[col];
        float vv[5];
#pragma unroll
        for (int k = 0; k < 5; ++k) vv[k] = v0[k * 128 + col];
#pragma unroll
        for (int r = 0; r < 4; ++r) {
          float val = fmaxf(acc[s][j][r] + b, 0.f);
#pragma unroll
          for (int k = 0; k < 5; ++k) p[k][r] = fmaf(val, vv[k], p[k][r]);
        }
      }
#pragma unroll
      for (int o = 1; o < 16; o <<= 1) {
#pragma unroll
        for (int k = 0; k < 5; ++k)
#pragma unroll
          for (int r = 0; r < 4; ++r) p[k][r] += __shfl_xor(p[k][r], o);
      }
      if (l16 == 0) {
#pragma unroll
        for (int r = 0; r < 4; ++r) {
          int m = rbase + r;
          if (m < N_NODES) {
#pragma unroll
            for (int k = 0; k < 5; ++k) hout[k * N_NODES + m] = p[k][r];
          }
        }
      }
    }
  }
}

extern "C" void kernel_launch(void* const* d_in, const int* in_sizes, int n_in,
                              void* d_out, int out_size, void* d_ws, size_t ws_size,
                              hipStream_t stream) {
  const void* x  = d_in[0];
  const int* ei  = (const int*)d_in[1];
  const void* w0 = d_in[2];
  const void* b0 = d_in[3];
  const void* w1 = d_in[4];
  const void* b1 = d_in[5];
  const void* w2 = d_in[6];
  const void* b2 = d_in[7];
  const void* wl = d_in[8];
  const void* bl = d_in[9];
  const int* src = ei;
  const int* dst = ei + N_EDGES;

  char* ws = (char*)d_ws;
  size_t off = 0;
  auto alloc = [&](size_t bytes) -> char* {
    char* p = ws + off;
    off += (bytes + 255) & ~(size_t)255;
    return p;
  };
  _Float16* T[5];
  for (int i = 0; i < 5; ++i) T[i] = (_Float16*)alloc(sizeof(_Float16) * N_NODES * FEAT);  // fp16 masters
  unsigned char* Q[5];
  for (int i = 0; i < 5; ++i) Q[i] = (unsigned char*)alloc((size_t)N_NODES * FEAT);        // int8 shadows
  float* S[5];
  for (int i = 0; i < 5; ++i) S[i] = (float*)alloc(sizeof(float) * N_NODES);               // row scales
  unsigned* edata = (unsigned*)alloc(sizeof(unsigned) * N_NODES * CAP);                    // 12.8 MB
  int* cnt = (int*)alloc(sizeof(int) * N_NODES * 2);  // cnt, deg contiguous (one memset)
  int* deg = cnt + N_NODES;
  _Float16* wt = (_Float16*)alloc(sizeof(_Float16) * NTRW);
  float* pf = (float*)alloc(sizeof(float) * 1536);
  float* hbuf = (float*)alloc(sizeof(float) * 5 * N_NODES);  // h_k = relu(H1).v_k
  float* bbuf = (float*)alloc(sizeof(float) * 3 * N_NODES);  // Clenshaw b3,b2,b1
  int* flag = (int*)alloc(sizeof(int));

  hipMemsetAsync(cnt, 0, sizeof(int) * N_NODES * 2, stream);
  k_pre1<<<1, 256, 0, stream>>>((const unsigned short*)x, b0, b1, b2, wl, bl, pf, flag);
  k_prev<<<3, 256, 0, stream>>>(w2, pf, flag);
  k_pre2<<<(NPRE + 255) / 256, 256, 0, stream>>>(x, w0, w1, src, dst, T[0], Q[0], S[0], wt, deg, flag);
  k_fill<<<(N_EDGES + 255) / 256, 256, 0, stream>>>(src, dst, deg, cnt, edata);

  int nblk_spmv = (N_NODES + 15) / 16;
  int nblk_gemm = (N_NODES + 127) / 128;
  const float* v = pf + 520;       // v_k, 5x128
  const float* cc = pf + 1160;     // b2.Wl + bl

  // layers 0,1: ChebConv via int8-shadow gathers; layer-0 GEMM -> relu rows (+shadow),
  // layer-1 GEMM -> h_k scalars only.
  for (int l = 0; l < 2; ++l) {
    k_spmv<<<nblk_spmv, 256, 0, stream>>>(edata, cnt, Q[0], S[0], nullptr, T[1], Q[1], S[1], 1.f, 0, 1);
    k_spmv<<<nblk_spmv, 256, 0, stream>>>(edata, cnt, Q[1], S[1], T[0], T[2], Q[2], S[2], 2.f, 1, 1);
    k_spmv<<<nblk_spmv, 256, 0, stream>>>(edata, cnt, Q[2], S[2], T[1], T[3], Q[3], S[3], 2.f, 1, 1);
    k_spmv<<<nblk_spmv, 256, 0, stream>>>(edata, cnt, Q[3], S[3], T[2], T[4], nullptr, nullptr, 2.f, 1, 0);
    k_gemm<<<nblk_gemm, 256, 0, stream>>>(T[0], T[1], T[2], T[3], T[4],
                                          wt + l * 5 * 16384, pf + l * 128, T[0],
                                          l, v, hbuf, Q[0], S[0]);
  }
  // layer 2 via Clenshaw on scalar fields (fp32)
  float* h0 = hbuf;
  float* h1 = hbuf + N_NODES;
  float* h2 = hbuf + 2 * N_NODES;
  float* h3 = hbuf + 3 * N_NODES;
  float* h4 = hbuf + 4 * N_NODES;
  float* b3 = bbuf;
  float* b2c = bbuf + N_NODES;
  float* b1c = bbuf + 2 * N_NODES;
  k_smv<<<nblk_spmv, 256, 0, stream>>>(edata, cnt, h3, h4, nullptr, 2.f, b3, 0, nullptr, flag, nullptr);
  k_smv<<<nblk_spmv, 256, 0, stream>>>(edata, cnt, h2, b3, h4, 2.f, b2c, 0, nullptr, flag, nullptr);
  k_smv<<<nblk_spmv, 256, 0, stream>>>(edata, cnt, h1, b2c, b3, 2.f, b1c, 0, nullptr, flag, nullptr);
  k_smv<<<nblk_spmv, 256, 0, stream>>>(edata, cnt, h0, b1c, b2c, 1.f, nullptr, 1, d_out, flag, cc);
}